// Round 12
// baseline (105.719 us; speedup 1.0000x reference)
//
#include <hip/hip_runtime.h>
#include <hip/hip_bf16.h>
#include <stdint.h>

typedef __bf16 bf16x8 __attribute__((ext_vector_type(8)));
typedef float f32x4 __attribute__((ext_vector_type(4)));

#define MAXD 40
#define ND   81
#define CSZ  256
#define HSZ  128
#define WSZ  416
#define HW   (HSZ * WSZ)

#define ALC   420      // dword row stride: 416 data + 4 pad; 4-row step = 1680 ≡ 16 (mod 32) -> 2-way free
#define RHALF 6720     // R region offset within a buffer (16*420)
#define BUFD  13440    // dwords per buffer (32 rows * 420)
#define NCHK  16       // 16 chunks of 16 channels
#define ESTR  420      // epilogue row stride

union U8 { uint32_t u[4]; bf16x8 v; };

static __device__ __forceinline__ uint32_t pk2(float a, float b) {
    union { __bf16 h[2]; uint32_t u; } v;
    v.h[0] = (__bf16)a; v.h[1] = (__bf16)b;
    return v.u;
}

// async global->LDS DMA, 16B/lane; LDS dst = wave-uniform base + lane*16
static __device__ __forceinline__ void gl16(const float* g, const float* l) {
    __builtin_amdgcn_global_load_lds(
        (const __attribute__((address_space(1))) void*)(uintptr_t)g,
        (__attribute__((address_space(3))) void*)(uint32_t)(uintptr_t)l,
        16, 0, 0);
}

__global__ __launch_bounds__(1024)
void corr_mfma_kernel(const float* __restrict__ left,
                      const float* __restrict__ right,
                      float* __restrict__ out) {
    __shared__ float Sh[3 * BUFD];   // 161280 B: 3 x (L[16][420] | R[16][420]) fp32 [c][w]

    const int t   = threadIdx.x;
    const int wv  = t >> 6;      // 0..15
    const int l   = t & 63;
    const int l15 = l & 15;
    const int l4  = l >> 4;      // 0..3
    const int b   = blockIdx.x >> 7;
    const int h   = blockIdx.x & 127;

    const size_t slab = ((size_t)b * CSZ) * HW + (size_t)h * WSZ;
    // per-lane global staging addrs: wave wv stages channel (16*ck + wv) of L and R
    const float* Lw = left  + slab + (size_t)wv * HW + 4 * l;
    const float* Rw = right + slab + (size_t)wv * HW + 4 * l;

    // wave owns p-pair {p0, p0+1}; tile (pi,k): r = p0+pi-5+k, j = 5-k
    const int p0 = 2 * wv;
    const bool hasP1 = (wv < 15);
    int cb[2]; bool okb[2];
    #pragma unroll
    for (int pi = 0; pi < 2; ++pi) {
        const int u = 16 * (p0 + pi) - MAXD + l15;
        okb[pi] = ((unsigned)u < (unsigned)WSZ);
        cb[pi]  = okb[pi] ? u : 0;
    }
    const int FB = 1680 * l4;    // (4*l4)*420 — lane's channel-row base within a buffer

    f32x4 acc0[6], acc1[6];
    #pragma unroll
    for (int k = 0; k < 6; ++k) { acc0[k] = (f32x4)0.0f; acc1[k] = (f32x4)0.0f; }

    uint2 aLo[7], bLo[2];

    // ---- prologue: stage chunk 0 -> buf0, chunk 1 -> buf1 ----
    #pragma unroll
    for (int c0 = 0; c0 < 2; ++c0) {
        const float* gL = Lw + (size_t)(16 * c0) * HW;
        const float* gR = Rw + (size_t)(16 * c0) * HW;
        const float* dL = &Sh[BUFD * c0 + wv * ALC];
        const float* dR = &Sh[BUFD * c0 + RHALF + wv * ALC];
        gl16(gL, dL); gl16(gR, dR);
        if (l < 40) { gl16(gL + 256, dL + 256); gl16(gR + 256, dR + 256); }
    }
    asm volatile("s_waitcnt vmcnt(4) lgkmcnt(0)" ::: "memory");  // chunk 0 landed
    __builtin_amdgcn_s_barrier();
    __builtin_amdgcn_sched_barrier(0);

    #pragma unroll
    for (int ck = 0; ck < NCHK; ++ck) {
        // ---- A) stage chunk ck+2 into buf (ck+2)%3 (rides across 2 phases) ----
        if (ck + 2 < NCHK) {
            const int buf = BUFD * ((ck + 2) % 3);
            const float* gL = Lw + (size_t)(16 * (ck + 2)) * HW;
            const float* gR = Rw + (size_t)(16 * (ck + 2)) * HW;
            const float* dL = &Sh[buf + wv * ALC];
            const float* dR = &Sh[buf + RHALF + wv * ALC];
            gl16(gL, dL); gl16(gR, dR);
            if (l < 40) { gl16(gL + 256, dL + 256); gl16(gR + 256, dR + 256); }
        }

        const int cbuf = BUFD * (ck % 3);

        if ((ck & 1) == 0) {
            // ---- even phase: capture LO halves of K=32 fragments ----
            #pragma unroll
            for (int pi = 0; pi < 2; ++pi) {
                if (pi == 0 || hasP1) {
                    float v0 = Sh[cbuf + RHALF + FB + 0 * ALC + cb[pi]];
                    float v1 = Sh[cbuf + RHALF + FB + 1 * ALC + cb[pi]];
                    float v2 = Sh[cbuf + RHALF + FB + 2 * ALC + cb[pi]];
                    float v3 = Sh[cbuf + RHALF + FB + 3 * ALC + cb[pi]];
                    if (!okb[pi]) { v0 = v1 = v2 = v3 = 0.0f; }
                    bLo[pi] = make_uint2(pk2(v0, v1), pk2(v2, v3));
                } else bLo[pi] = make_uint2(0u, 0u);
            }
            #pragma unroll
            for (int a = 0; a < 7; ++a) {
                const int r = p0 - 5 + a;
                if (r >= 0 && r <= 25) {
                    const int col = 16 * r + l15;
                    const float v0 = Sh[cbuf + FB + 0 * ALC + col];
                    const float v1 = Sh[cbuf + FB + 1 * ALC + col];
                    const float v2 = Sh[cbuf + FB + 2 * ALC + col];
                    const float v3 = Sh[cbuf + FB + 3 * ALC + col];
                    aLo[a] = make_uint2(pk2(v0, v1), pk2(v2, v3));
                } else aLo[a] = make_uint2(0u, 0u);
            }
        } else {
            // ---- odd phase: HI halves, assemble K=32, MFMA ----
            bf16x8 bF[2];
            #pragma unroll
            for (int pi = 0; pi < 2; ++pi) {
                if (pi == 0 || hasP1) {
                    float v0 = Sh[cbuf + RHALF + FB + 0 * ALC + cb[pi]];
                    float v1 = Sh[cbuf + RHALF + FB + 1 * ALC + cb[pi]];
                    float v2 = Sh[cbuf + RHALF + FB + 2 * ALC + cb[pi]];
                    float v3 = Sh[cbuf + RHALF + FB + 3 * ALC + cb[pi]];
                    if (!okb[pi]) { v0 = v1 = v2 = v3 = 0.0f; }
                    U8 x; x.u[0] = bLo[pi].x; x.u[1] = bLo[pi].y;
                    x.u[2] = pk2(v0, v1); x.u[3] = pk2(v2, v3);
                    bF[pi] = x.v;
                } else {
                    U8 z; z.u[0] = z.u[1] = z.u[2] = z.u[3] = 0u;
                    bF[pi] = z.v;
                }
            }
            #pragma unroll
            for (int a = 0; a < 7; ++a) {
                const int r = p0 - 5 + a;
                if (r >= 0 && r <= 25) {
                    const int col = 16 * r + l15;
                    const float v0 = Sh[cbuf + FB + 0 * ALC + col];
                    const float v1 = Sh[cbuf + FB + 1 * ALC + col];
                    const float v2 = Sh[cbuf + FB + 2 * ALC + col];
                    const float v3 = Sh[cbuf + FB + 3 * ALC + col];
                    U8 x; x.u[0] = aLo[a].x; x.u[1] = aLo[a].y;
                    x.u[2] = pk2(v0, v1); x.u[3] = pk2(v2, v3);
                    if (a < 6)
                        acc0[a] = __builtin_amdgcn_mfma_f32_16x16x32_bf16(x.v, bF[0], acc0[a], 0, 0, 0);
                    if (hasP1 && a >= 1)
                        acc1[a - 1] = __builtin_amdgcn_mfma_f32_16x16x32_bf16(x.v, bF[1], acc1[a - 1], 0, 0, 0);
                }
            }
        }

        // ---- phase end: counted vmcnt — only chunk ck+2's 4 DMA ops may remain ----
        if (ck + 2 < NCHK) {
            asm volatile("s_waitcnt vmcnt(4) lgkmcnt(0)" ::: "memory");
        } else {
            asm volatile("s_waitcnt vmcnt(0) lgkmcnt(0)" ::: "memory");
        }
        __builtin_amdgcn_s_barrier();
        __builtin_amdgcn_sched_barrier(0);
    }

    // ---- epilogue: 2 d-groups; scatter acc -> LDS, contiguous f32x4 stores ----
    const float scale = 1.0f / 256.0f;
    float* outp = out + (size_t)b * ND * HW + (size_t)h * WSZ;

    #pragma unroll
    for (int gph = 0; gph < 2; ++gph) {
        const int d0 = gph * 41;
        const int dn = gph ? 40 : 41;

        #pragma unroll
        for (int pi = 0; pi < 2; ++pi) {
            if (pi == 0 || hasP1) {
                #pragma unroll
                for (int k = 0; k < 6; ++k) {
                    const int r = p0 - 5 + pi + k;
                    if (r >= 0 && r <= 25) {
                        const int j = 5 - k;
                        const f32x4 av = pi ? acc1[k] : acc0[k];
                        #pragma unroll
                        for (int rr = 0; rr < 4; ++rr) {
                            const int mm = 4 * l4 + rr;
                            const int d  = 16 * j + l15 - mm;
                            if ((unsigned)(d - d0) < (unsigned)dn)
                                Sh[(d - d0) * ESTR + 16 * r + mm] = av[rr] * scale;
                        }
                    }
                }
            }
        }
        asm volatile("s_waitcnt lgkmcnt(0)" ::: "memory");
        __builtin_amdgcn_s_barrier();
        __builtin_amdgcn_sched_barrier(0);

        #pragma unroll
        for (int i = 0; i < 5; ++i) {
            const int idx = i * 1024 + t;
            if (idx < dn * 104) {
                const int d = idx / 104;
                const int q = idx - 104 * d;
                *(f32x4*)(outp + (size_t)(d0 + d) * HW + 4 * q) = *(const f32x4*)&Sh[d * ESTR + 4 * q];
            }
        }
        if (gph == 0) {
            asm volatile("s_waitcnt lgkmcnt(0)" ::: "memory");
            __builtin_amdgcn_s_barrier();
            __builtin_amdgcn_sched_barrier(0);
        }
    }
}

extern "C" void kernel_launch(void* const* d_in, const int* in_sizes, int n_in,
                              void* d_out, int out_size, void* d_ws, size_t ws_size,
                              hipStream_t stream) {
    const float* left  = (const float*)d_in[0];
    const float* right = (const float*)d_in[1];
    float* out = (float*)d_out;
    (void)in_sizes; (void)n_in; (void)out_size; (void)d_ws; (void)ws_size;
    corr_mfma_kernel<<<dim3(4 * 128), dim3(1024), 0, stream>>>(left, right, out);
}